// Round 12
// baseline (133.312 us; speedup 1.0000x reference)
//
#include <hip/hip_runtime.h>
#include <hip/hip_bf16.h>

#define DIM 2048
#define NB  64
#define KSL 4          // K-split slices for qkv GEMM (512 k per block, 2 chunks)
#define JSL 8          // j-split slices for attention (256-j slices)

typedef short bf16x8 __attribute__((ext_vector_type(8)));
typedef short s16x4  __attribute__((ext_vector_type(4)));
typedef float f32x4  __attribute__((ext_vector_type(4)));
typedef float f32x2  __attribute__((ext_vector_type(2)));

__device__ __forceinline__ unsigned short f32_to_bf16_rne(float f) {
  unsigned u = __builtin_bit_cast(unsigned, f);
  unsigned r = u + 0x7FFF + ((u >> 16) & 1);
  return (unsigned short)(r >> 16);
}

// x -> hi/lo bf16 in MFMA-fragment order (coalesced A loads in qkv_mfma)
__global__ __launch_bounds__(256)
void prep(const float* __restrict__ x, unsigned short* __restrict__ xrh,
          unsigned short* __restrict__ xrl) {
  const int tg = blockIdx.x * 256 + threadIdx.x;   // [0, 32768)
  const int b = tg >> 9;
  const int k = (tg & 511) * 4;
  float4 f = *(const float4*)(x + (size_t)b * DIM + k);
  const int mt = b >> 4, l15 = b & 15;
  const int ck = k >> 5, quad = (k >> 3) & 3, u = k & 7;
  const size_t off = (((size_t)(mt * 64 + ck) * 64) + quad * 16 + l15) * 8 + u;
  float vf[4] = {f.x, f.y, f.z, f.w};
  ushort4 h4, l4;
  unsigned short* hp = &h4.x;
  unsigned short* lp = &l4.x;
#pragma unroll
  for (int e = 0; e < 4; ++e) {
    unsigned short h = f32_to_bf16_rne(vf[e]);
    float hf = __builtin_bit_cast(float, ((unsigned)h) << 16);
    hp[e] = h;
    lp[e] = f32_to_bf16_rne(vf[e] - hf);
  }
  *(ushort4*)(xrh + off) = h4;
  *(ushort4*)(xrl + off) = l4;
}

#define WSTR 260   // LDS row stride (shorts): 130 dwords == 2 mod 32 -> 4-way max

// C[b][j] = sum_k x[b][k]*W[j][k].  MFMA 16x16x32 bf16, 3-term hi/lo split.
// R12: 16-row j-tiles -> grid (128, KSL, 3) = 1536 blocks = 6 waves/SIMD
// (2x R11) to hide the ~900cyc HBM latency on the W stream.  Block = 4 waves
// sharing one 16-row W tile (LDS 16.6 KB); wave <-> one 16-b m-tile.
// 512 k per block in two 256-k chunks, chunk-1 W register-prefetched over
// chunk-0 compute.  Writes per-slice partials part[sl][mat][b][j].
__global__ __launch_bounds__(256)
void qkv_mfma(const unsigned short* __restrict__ xrh,
              const unsigned short* __restrict__ xrl,
              const float* __restrict__ Wq, const float* __restrict__ Wk,
              const float* __restrict__ Wv, float* __restrict__ part) {
  const int mat = blockIdx.z;
  const float* __restrict__ W = (mat == 0) ? Wq : ((mat == 1) ? Wk : Wv);
  const int t = threadIdx.x;
  const int wave = t >> 6, lane = t & 63;
  const int l15 = lane & 15, quad = lane >> 4;
  const int j0 = blockIdx.x * 16;                  // 16 j rows per block
  const int kb0 = blockIdx.y * 512;
  const int mt = wave;                             // wave <-> m-tile

  __shared__ __align__(16) short wh[16][WSTR];
  __shared__ __align__(16) short wl[16][WSTR];

  // staging map: thread t -> row r = t>>4, 16 consecutive floats at col cb
  const int r = t >> 4;
  const int cb = (t & 15) * 16;
  const float* __restrict__ wrow = W + (size_t)(j0 + r) * DIM + kb0 + cb;

  f32x4 acc = {0.f, 0.f, 0.f, 0.f};
  float4 wa[4], wb[4];
#pragma unroll
  for (int p = 0; p < 4; ++p) wa[p] = *(const float4*)(wrow + p * 4);

#pragma unroll
  for (int c = 0; c < 2; ++c) {
    // convert + store this chunk's W tile (trunc-hi / trunc-lo split)
#pragma unroll
    for (int p = 0; p < 4; ++p) {
      float4 w4 = (c == 0) ? wa[p] : wb[p];
      float wf[4] = {w4.x, w4.y, w4.z, w4.w};
      s16x4 h4, l4;
#pragma unroll
      for (int e = 0; e < 4; ++e) {
        unsigned uu = __builtin_bit_cast(unsigned, wf[e]);
        h4[e] = (short)(uu >> 16);
        float hf = __builtin_bit_cast(float, uu & 0xFFFF0000u);
        float res = wf[e] - hf;
        l4[e] = (short)(__builtin_bit_cast(unsigned, res) >> 16);
      }
      *(s16x4*)&wh[r][cb + p * 4] = h4;
      *(s16x4*)&wl[r][cb + p * 4] = l4;
    }
    if (c == 0) {
#pragma unroll
      for (int p = 0; p < 4; ++p)
        wb[p] = *(const float4*)(wrow + 256 + p * 4);   // in flight over compute
    }
    __syncthreads();

    const int ckb = blockIdx.y * 16 + c * 8;
#pragma unroll
    for (int kk = 0; kk < 8; ++kk) {
      bf16x8 whf, wlf;
      *(s16x4*)&whf       = *(const s16x4*)&wh[l15][kk * 32 + quad * 8];
      *(((s16x4*)&whf)+1) = *(const s16x4*)&wh[l15][kk * 32 + quad * 8 + 4];
      *(s16x4*)&wlf       = *(const s16x4*)&wl[l15][kk * 32 + quad * 8];
      *(((s16x4*)&wlf)+1) = *(const s16x4*)&wl[l15][kk * 32 + quad * 8 + 4];
      const size_t xo = (((size_t)(mt * 64 + ckb + kk)) * 64 + lane) * 8;
      bf16x8 ah = *(const bf16x8*)(xrh + xo);       // base + lane*16B: coalesced
      bf16x8 al = *(const bf16x8*)(xrl + xo);
      acc = __builtin_amdgcn_mfma_f32_16x16x32_bf16(ah, whf, acc, 0, 0, 0);
      acc = __builtin_amdgcn_mfma_f32_16x16x32_bf16(al, whf, acc, 0, 0, 0);
      acc = __builtin_amdgcn_mfma_f32_16x16x32_bf16(ah, wlf, acc, 0, 0, 0);
    }
    if (c == 0) __syncthreads();                    // protect LDS overwrite
  }

  // D layout (verified R2-R11): col(j)=lane&15, row(b)=quad*4+reg
  float* __restrict__ pb =
      part + ((size_t)(blockIdx.y * 3 + mat) * NB) * DIM + j0 + l15;
#pragma unroll
  for (int rr = 0; rr < 4; ++rr) {
    const int b = mt * 16 + quad * 4 + rr;
    pb[(size_t)b * DIM] = acc[rr];
  }
}

// out[b][i] partials over a 256-j slice; K-slice reduction of q,k,v folded in.
// TWO i-values per thread keeps main pipe (96 cyc/8j) under trans pipe
// (128 cyc/8j); grid (4, JSL, 64) = 2048 blocks -> 32 waves/CU hides LDS
// latency.  NO max subtraction (|c*k| <~ 29, fp32-safe; validated R4-R11).
__global__ __launch_bounds__(256)
void attn(const float* __restrict__ part, f32x2* __restrict__ pnd) {
  const int b = blockIdx.z, js = blockIdx.y, t = threadIdx.x;
  const int i0 = blockIdx.x * 512;                 // 512 i per block, 2/thread
  const int ia = i0 + t, ib = i0 + 256 + t;
  const int jb = js * (DIM / JSL);                 // 256-j slice

  __shared__ __align__(16) float ks[DIM / JSL];
  __shared__ __align__(16) float vs[DIM / JSL];

  float kv = 0.f, vv = 0.f, qa = 0.f, qb = 0.f;
#pragma unroll
  for (int sl = 0; sl < KSL; ++sl) {
    kv += part[((size_t)(sl * 3 + 1) * NB + b) * DIM + jb + t];
    vv += part[((size_t)(sl * 3 + 2) * NB + b) * DIM + jb + t];
    qa += part[((size_t)(sl * 3 + 0) * NB + b) * DIM + ia];
    qb += part[((size_t)(sl * 3 + 0) * NB + b) * DIM + ib];
  }
  ks[t] = kv;
  vs[t] = vv;
  __syncthreads();

  const float ca = qa * 1.4426950408889634f;
  const float cb = qb * 1.4426950408889634f;
  float na0=0.f, na1=0.f, da0=0.f, da1=0.f;
  float nb0=0.f, nb1=0.f, db0=0.f, db1=0.f;
#pragma unroll 4
  for (int j = 0; j < DIM / JSL; j += 8) {
    float4 k0 = *(const float4*)(ks + j);        // uniform addr: LDS broadcast
    float4 k1 = *(const float4*)(ks + j + 4);
    float4 v0 = *(const float4*)(vs + j);
    float4 v1 = *(const float4*)(vs + j + 4);
    float kf[8] = {k0.x,k0.y,k0.z,k0.w,k1.x,k1.y,k1.z,k1.w};
    float vf[8] = {v0.x,v0.y,v0.z,v0.w,v1.x,v1.y,v1.z,v1.w};
#pragma unroll
    for (int u = 0; u < 8; ++u) {
      float ea = __builtin_amdgcn_exp2f(ca * kf[u]);
      float eb = __builtin_amdgcn_exp2f(cb * kf[u]);
      if (u & 1) {
        da1 += ea; na1 = fmaf(ea, vf[u], na1);
        db1 += eb; nb1 = fmaf(eb, vf[u], nb1);
      } else {
        da0 += ea; na0 = fmaf(ea, vf[u], na0);
        db0 += eb; nb0 = fmaf(eb, vf[u], nb0);
      }
    }
  }
  f32x2 nda, ndb;
  nda.x = na0 + na1; nda.y = da0 + da1;
  ndb.x = nb0 + nb1; ndb.y = db0 + db1;
  pnd[((size_t)b * JSL + js) * DIM + ia] = nda;
  pnd[((size_t)b * JSL + js) * DIM + ib] = ndb;
}

__global__ __launch_bounds__(256)
void attn_fin(const f32x2* __restrict__ pnd, float* __restrict__ out) {
  const int b = blockIdx.y;
  const int i = blockIdx.x * 256 + threadIdx.x;
  float n = 0.f, d = 0.f;
#pragma unroll
  for (int s = 0; s < JSL; ++s) {
    f32x2 p = pnd[((size_t)b * JSL + s) * DIM + i];
    n += p.x; d += p.y;
  }
  out[(size_t)b * DIM + i] = n / d;
}

extern "C" void kernel_launch(void* const* d_in, const int* in_sizes, int n_in,
                              void* d_out, int out_size, void* d_ws, size_t ws_size,
                              hipStream_t stream) {
  const float* x  = (const float*)d_in[0];
  const float* Wq = (const float*)d_in[1];
  const float* Wk = (const float*)d_in[2];
  const float* Wv = (const float*)d_in[3];
  float* out = (float*)d_out;

  char* w = (char*)d_ws;
  unsigned short* xrh = (unsigned short*)w;                  // 256 KB
  unsigned short* xrl = (unsigned short*)(w + (512 << 10));  // 256 KB
  float* part = (float*)(w + (1 << 20));                     // 6.3 MB (KSL=4)
  f32x2* pnd  = (f32x2*)(w + (16 << 20));                    // 8 MB (JSL=8)

  hipLaunchKernelGGL(prep, dim3(128), dim3(256), 0, stream, x, xrh, xrl);
  hipLaunchKernelGGL(qkv_mfma, dim3(128, KSL, 3), dim3(256), 0, stream,
                     xrh, xrl, Wq, Wk, Wv, part);
  hipLaunchKernelGGL(attn, dim3(4, JSL, NB), dim3(256), 0, stream, part, pnd);
  hipLaunchKernelGGL(attn_fin, dim3(8, NB), dim3(256), 0, stream, pnd, out);
}

// Round 13
// 131.481 us; speedup vs baseline: 1.0139x; 1.0139x over previous
//
#include <hip/hip_runtime.h>
#include <hip/hip_bf16.h>

#define DIM 2048
#define NB  64
#define KSL 4          // K-split slices for qkv GEMM (512 k per block, 2 chunks)
#define JSL 8          // j-split slices for attention (256-j slices)

typedef short bf16x8 __attribute__((ext_vector_type(8)));
typedef short s16x4  __attribute__((ext_vector_type(4)));
typedef float f32x4  __attribute__((ext_vector_type(4)));
typedef float f32x2  __attribute__((ext_vector_type(2)));

__device__ __forceinline__ unsigned short f32_to_bf16_rne(float f) {
  unsigned u = __builtin_bit_cast(unsigned, f);
  unsigned r = u + 0x7FFF + ((u >> 16) & 1);
  return (unsigned short)(r >> 16);
}

// x -> hi/lo bf16 in MFMA-fragment order (coalesced A loads in qkv_mfma)
__global__ __launch_bounds__(256)
void prep(const float* __restrict__ x, unsigned short* __restrict__ xrh,
          unsigned short* __restrict__ xrl) {
  const int tg = blockIdx.x * 256 + threadIdx.x;   // [0, 32768)
  const int b = tg >> 9;
  const int k = (tg & 511) * 4;
  float4 f = *(const float4*)(x + (size_t)b * DIM + k);
  const int mt = b >> 4, l15 = b & 15;
  const int ck = k >> 5, quad = (k >> 3) & 3, u = k & 7;
  const size_t off = (((size_t)(mt * 64 + ck) * 64) + quad * 16 + l15) * 8 + u;
  float vf[4] = {f.x, f.y, f.z, f.w};
  ushort4 h4, l4;
  unsigned short* hp = &h4.x;
  unsigned short* lp = &l4.x;
#pragma unroll
  for (int e = 0; e < 4; ++e) {
    unsigned short h = f32_to_bf16_rne(vf[e]);
    float hf = __builtin_bit_cast(float, ((unsigned)h) << 16);
    hp[e] = h;
    lp[e] = f32_to_bf16_rne(vf[e] - hf);
  }
  *(ushort4*)(xrh + off) = h4;
  *(ushort4*)(xrl + off) = l4;
}

#define WSTR 260   // LDS row stride (shorts): 130 dwords == 2 mod 32 -> 4-way max

__device__ __forceinline__ void conv_store_w(short (*wh)[WSTR], short (*wl)[WSTR],
                                             const float4* wreg, int wave, int lane) {
#pragma unroll
  for (int p = 0; p < 8; ++p) {
    const int r = p * 4 + wave;
    float wf[4] = {wreg[p].x, wreg[p].y, wreg[p].z, wreg[p].w};
    s16x4 h4, l4;
#pragma unroll
    for (int e = 0; e < 4; ++e) {
      unsigned uu = __builtin_bit_cast(unsigned, wf[e]);
      h4[e] = (short)(uu >> 16);                              // trunc hi
      float hf = __builtin_bit_cast(float, uu & 0xFFFF0000u);
      float res = wf[e] - hf;
      l4[e] = (short)(__builtin_bit_cast(unsigned, res) >> 16);  // trunc lo
    }
    *(s16x4*)&wh[r][lane * 4] = h4;
    *(s16x4*)&wl[r][lane * 4] = l4;
  }
}

// C[b][j] = sum_k x[b][k]*W[j][k].  MFMA 16x16x32 bf16, 3-term hi/lo split.
// R11-measured-best config (R12's 16-row variant was neutral; reverted).
// Grid (64, KSL, 3); 512 k per block, chunk-1 W register-prefetched over
// chunk-0 compute.  Writes per-slice partials part[sl][mat][b][j].
__global__ __launch_bounds__(256)
void qkv_mfma(const unsigned short* __restrict__ xrh,
              const unsigned short* __restrict__ xrl,
              const float* __restrict__ Wq, const float* __restrict__ Wk,
              const float* __restrict__ Wv, float* __restrict__ part) {
  const int mat = blockIdx.z;
  const float* __restrict__ W = (mat == 0) ? Wq : ((mat == 1) ? Wk : Wv);
  const int t = threadIdx.x;
  const int wave = t >> 6, lane = t & 63;
  const int l15 = lane & 15, quad = lane >> 4;
  const int j0 = blockIdx.x * 32;
  const int kb0 = blockIdx.y * 512;

  __shared__ __align__(16) short wh[32][WSTR];
  __shared__ __align__(16) short wl[32][WSTR];

  const int jh = wave & 1;
  const int mh = wave >> 1;
  const int frow = jh * 16 + l15;
  f32x4 acc[2] = {{0.f,0.f,0.f,0.f},{0.f,0.f,0.f,0.f}};

  float4 wa[8], wb[8];
#pragma unroll
  for (int p = 0; p < 8; ++p)
    wa[p] = *(const float4*)(W + (size_t)(j0 + p * 4 + wave) * DIM + kb0 + lane * 4);

#pragma unroll
  for (int c = 0; c < 2; ++c) {
    if (c == 0) conv_store_w(wh, wl, wa, wave, lane);
    else        conv_store_w(wh, wl, wb, wave, lane);
    if (c == 0) {
#pragma unroll
      for (int p = 0; p < 8; ++p)
        wb[p] = *(const float4*)(W + (size_t)(j0 + p * 4 + wave) * DIM +
                                 kb0 + 256 + lane * 4);   // in flight over compute
    }
    __syncthreads();

    const int ckb = blockIdx.y * 16 + c * 8;
#pragma unroll
    for (int kk = 0; kk < 8; ++kk) {
      bf16x8 whf, wlf;
      *(s16x4*)&whf       = *(const s16x4*)&wh[frow][kk * 32 + quad * 8];
      *(((s16x4*)&whf)+1) = *(const s16x4*)&wh[frow][kk * 32 + quad * 8 + 4];
      *(s16x4*)&wlf       = *(const s16x4*)&wl[frow][kk * 32 + quad * 8];
      *(((s16x4*)&wlf)+1) = *(const s16x4*)&wl[frow][kk * 32 + quad * 8 + 4];
      const int ck = ckb + kk;
#pragma unroll
      for (int u = 0; u < 2; ++u) {
        const int mt = mh * 2 + u;
        const size_t xo = (((size_t)(mt * 64 + ck)) * 64 + lane) * 8;
        bf16x8 ah = *(const bf16x8*)(xrh + xo);
        bf16x8 al = *(const bf16x8*)(xrl + xo);
        acc[u] = __builtin_amdgcn_mfma_f32_16x16x32_bf16(ah, whf, acc[u], 0, 0, 0);
        acc[u] = __builtin_amdgcn_mfma_f32_16x16x32_bf16(al, whf, acc[u], 0, 0, 0);
        acc[u] = __builtin_amdgcn_mfma_f32_16x16x32_bf16(ah, wlf, acc[u], 0, 0, 0);
      }
    }
    if (c == 0) __syncthreads();
  }

  // D layout (verified R2-R12): col(j)=lane&15, row(b)=quad*4+reg
  float* __restrict__ pb =
      part + ((size_t)(blockIdx.y * 3 + mat) * NB) * DIM + j0 + jh * 16 + l15;
#pragma unroll
  for (int u = 0; u < 2; ++u)
#pragma unroll
    for (int r = 0; r < 4; ++r) {
      const int b = (mh * 2 + u) * 16 + quad * 4 + r;
      pb[(size_t)b * DIM] = acc[u][r];
    }
}

// out[b][i] partials over a 256-j slice; K-slice reduction folded in.
// TWO i per thread + PACKED fp32 math (v_pk_mul/add/fma): per 8-j iter the
// main pipe is 24 pk-instrs + 4 ds_read = ~88 issue-cyc, under the 128
// trans-cyc of 16 exps -> cleanly trans-pipe-bound (R11 was 136 issue-cyc,
// marginally issue-bound).  Grid (4, JSL, 64) = 2048 blocks = 32 waves/CU.
// NO max subtraction (|c*k| <~ 29, fp32-safe; validated R4-R12).
__global__ __launch_bounds__(256)
void attn(const float* __restrict__ part, f32x2* __restrict__ pnd) {
  const int b = blockIdx.z, js = blockIdx.y, t = threadIdx.x;
  const int i0 = blockIdx.x * 512;                 // 512 i per block, 2/thread
  const int ia = i0 + t, ib = i0 + 256 + t;
  const int jb = js * (DIM / JSL);                 // 256-j slice

  __shared__ __align__(16) float ks[DIM / JSL];
  __shared__ __align__(16) float vs[DIM / JSL];

  float kv = 0.f, vv = 0.f, qa = 0.f, qb = 0.f;
#pragma unroll
  for (int sl = 0; sl < KSL; ++sl) {
    kv += part[((size_t)(sl * 3 + 1) * NB + b) * DIM + jb + t];
    vv += part[((size_t)(sl * 3 + 2) * NB + b) * DIM + jb + t];
    qa += part[((size_t)(sl * 3 + 0) * NB + b) * DIM + ia];
    qb += part[((size_t)(sl * 3 + 0) * NB + b) * DIM + ib];
  }
  ks[t] = kv;
  vs[t] = vv;
  __syncthreads();

  const float ca = qa * 1.4426950408889634f;
  const float cb = qb * 1.4426950408889634f;
  const f32x2 ca2 = {ca, ca}, cb2 = {cb, cb};

  f32x2 na0 = {0.f,0.f}, na1 = {0.f,0.f}, da0 = {0.f,0.f}, da1 = {0.f,0.f};
  f32x2 nb0 = {0.f,0.f}, nb1 = {0.f,0.f}, db0 = {0.f,0.f}, db1 = {0.f,0.f};
#pragma unroll 4
  for (int j = 0; j < DIM / JSL; j += 8) {
    f32x2 k01 = *(const f32x2*)(ks + j);
    f32x2 k23 = *(const f32x2*)(ks + j + 2);
    f32x2 k45 = *(const f32x2*)(ks + j + 4);
    f32x2 k67 = *(const f32x2*)(ks + j + 6);
    f32x2 v01 = *(const f32x2*)(vs + j);
    f32x2 v23 = *(const f32x2*)(vs + j + 2);
    f32x2 v45 = *(const f32x2*)(vs + j + 4);
    f32x2 v67 = *(const f32x2*)(vs + j + 6);
    // i = ia
    f32x2 p0 = ca2 * k01, p1 = ca2 * k23, p2 = ca2 * k45, p3 = ca2 * k67;
    f32x2 e0, e1, e2, e3;
    e0.x = __builtin_amdgcn_exp2f(p0.x); e0.y = __builtin_amdgcn_exp2f(p0.y);
    e1.x = __builtin_amdgcn_exp2f(p1.x); e1.y = __builtin_amdgcn_exp2f(p1.y);
    e2.x = __builtin_amdgcn_exp2f(p2.x); e2.y = __builtin_amdgcn_exp2f(p2.y);
    e3.x = __builtin_amdgcn_exp2f(p3.x); e3.y = __builtin_amdgcn_exp2f(p3.y);
    da0 += e0; da1 += e1; da0 += e2; da1 += e3;
    na0 = __builtin_elementwise_fma(e0, v01, na0);
    na1 = __builtin_elementwise_fma(e1, v23, na1);
    na0 = __builtin_elementwise_fma(e2, v45, na0);
    na1 = __builtin_elementwise_fma(e3, v67, na1);
    // i = ib
    f32x2 r0 = cb2 * k01, r1 = cb2 * k23, r2 = cb2 * k45, r3 = cb2 * k67;
    f32x2 f0, f1, f2, f3;
    f0.x = __builtin_amdgcn_exp2f(r0.x); f0.y = __builtin_amdgcn_exp2f(r0.y);
    f1.x = __builtin_amdgcn_exp2f(r1.x); f1.y = __builtin_amdgcn_exp2f(r1.y);
    f2.x = __builtin_amdgcn_exp2f(r2.x); f2.y = __builtin_amdgcn_exp2f(r2.y);
    f3.x = __builtin_amdgcn_exp2f(r3.x); f3.y = __builtin_amdgcn_exp2f(r3.y);
    db0 += f0; db1 += f1; db0 += f2; db1 += f3;
    nb0 = __builtin_elementwise_fma(f0, v01, nb0);
    nb1 = __builtin_elementwise_fma(f1, v23, nb1);
    nb0 = __builtin_elementwise_fma(f2, v45, nb0);
    nb1 = __builtin_elementwise_fma(f3, v67, nb1);
  }
  f32x2 nda, ndb;
  nda.x = (na0.x + na0.y) + (na1.x + na1.y);
  nda.y = (da0.x + da0.y) + (da1.x + da1.y);
  ndb.x = (nb0.x + nb0.y) + (nb1.x + nb1.y);
  ndb.y = (db0.x + db0.y) + (db1.x + db1.y);
  pnd[((size_t)b * JSL + js) * DIM + ia] = nda;
  pnd[((size_t)b * JSL + js) * DIM + ib] = ndb;
}

__global__ __launch_bounds__(256)
void attn_fin(const f32x2* __restrict__ pnd, float* __restrict__ out) {
  const int b = blockIdx.y;
  const int i = blockIdx.x * 256 + threadIdx.x;
  float n = 0.f, d = 0.f;
#pragma unroll
  for (int s = 0; s < JSL; ++s) {
    f32x2 p = pnd[((size_t)b * JSL + s) * DIM + i];
    n += p.x; d += p.y;
  }
  out[(size_t)b * DIM + i] = n / d;
}

extern "C" void kernel_launch(void* const* d_in, const int* in_sizes, int n_in,
                              void* d_out, int out_size, void* d_ws, size_t ws_size,
                              hipStream_t stream) {
  const float* x  = (const float*)d_in[0];
  const float* Wq = (const float*)d_in[1];
  const float* Wk = (const float*)d_in[2];
  const float* Wv = (const float*)d_in[3];
  float* out = (float*)d_out;

  char* w = (char*)d_ws;
  unsigned short* xrh = (unsigned short*)w;                  // 256 KB
  unsigned short* xrl = (unsigned short*)(w + (512 << 10));  // 256 KB
  float* part = (float*)(w + (1 << 20));                     // 6.3 MB (KSL=4)
  f32x2* pnd  = (f32x2*)(w + (16 << 20));                    // 8 MB (JSL=8)

  hipLaunchKernelGGL(prep, dim3(128), dim3(256), 0, stream, x, xrh, xrl);
  hipLaunchKernelGGL(qkv_mfma, dim3(64, KSL, 3), dim3(256), 0, stream,
                     xrh, xrl, Wq, Wk, Wv, part);
  hipLaunchKernelGGL(attn, dim3(4, JSL, NB), dim3(256), 0, stream, part, pnd);
  hipLaunchKernelGGL(attn_fin, dim3(8, NB), dim3(256), 0, stream, pnd, out);
}